// Round 6
// baseline (446.831 us; speedup 1.0000x reference)
//
#include <hip/hip_runtime.h>
#include <hip/hip_bf16.h>
#include <math.h>

typedef __bf16 bf16x8 __attribute__((ext_vector_type(8)));
typedef float f32x4 __attribute__((ext_vector_type(4)));

#define AS1 __attribute__((address_space(1)))
#define AS3 __attribute__((address_space(3)))
typedef AS1 const void gvoid;
typedef AS3 void svoid;

namespace {
constexpr int Bc = 4, Lc = 1024, Dc = 768, Hc = 12, HDc = 64;
constexpr int NKT = 24;          // K tiles: 768 / 32
}

static __device__ __forceinline__ ushort f2bf(float f) {
    __hip_bfloat16 h = __float2bfloat16(f);
    return *reinterpret_cast<ushort*>(&h);
}
static __device__ __forceinline__ float bf2f(ushort u) {
    __hip_bfloat16 h;
    *reinterpret_cast<ushort*>(&h) = u;
    return __bfloat162float(h);
}

// offset (ushort units) within an 8 KB [128 rows][32 cols] bf16 tile,
// paired-row XOR swizzle: 2 lanes/bank on ds_read_b128 (conflict-free min).
static __device__ __forceinline__ int sw_us(int row, int col) {
    int line = row >> 1;
    int slot = (((row & 1) << 2) + (col >> 3)) ^ (line & 7);
    return line * 64 + slot * 8 + (col & 7);
}

// ------- fp32 -> bf16 convert (dist_emb), zero-pad to 2048 rows ------------
__global__ void cvt_bf16_k(const float* __restrict__ in, ushort* __restrict__ out,
                           int n, int ntot) {
    int i = blockIdx.x * 256 + threadIdx.x;
    if (i < ntot) out[i] = (i < n) ? f2bf(in[i]) : (ushort)0;
}

// ---------------- hs [4096,768] fp32 -> tiled swizzled hi/lo ---------------
__global__ __launch_bounds__(256) void prep_hs(const float* __restrict__ hs,
                                               ushort* __restrict__ oh,
                                               ushort* __restrict__ ol) {
    int i = blockIdx.x * 256 + threadIdx.x;      // 4096*96
    int m = i / 96, c8 = i % 96;
    const float* src = hs + (size_t)m * Dc + c8 * 8;
    float4 x0 = *(const float4*)src;
    float4 x1 = *(const float4*)(src + 4);
    float xs[8] = {x0.x, x0.y, x0.z, x0.w, x1.x, x1.y, x1.z, x1.w};
    ushort hi[8], lo[8];
#pragma unroll
    for (int j = 0; j < 8; ++j) {
        hi[j] = f2bf(xs[j]);
        lo[j] = f2bf(xs[j] - bf2f(hi[j]));
    }
    int col = c8 * 8, kt = col >> 5, kc = col & 31;
    int mt = m >> 7, row = m & 127;
    int off = (mt * NKT + kt) * 4096 + sw_us(row, kc);
    *(uint4*)(oh + off) = *(uint4*)hi;
    *(uint4*)(ol + off) = *(uint4*)lo;
}

// ---------------- W^T tiles: Wq|Wk|Wv packed [2304 n], Wd [768 n] ----------
__global__ __launch_bounds__(256) void prep_w(
    const float* __restrict__ Wq, const float* __restrict__ Wk,
    const float* __restrict__ Wv, const float* __restrict__ Wd,
    ushort* __restrict__ qkvh, ushort* __restrict__ qkvl,
    ushort* __restrict__ wdh, ushort* __restrict__ wdl) {
    int i = blockIdx.x * 256 + threadIdx.x;      // 768*384
    int k = i / 384, n8 = i % 384;
    int which = n8 / 96, nl = (n8 % 96) * 8;
    const float* W = which == 0 ? Wq : which == 1 ? Wk : which == 2 ? Wv : Wd;
    const float* src = W + (size_t)k * Dc + nl;
    float4 x0 = *(const float4*)src;
    float4 x1 = *(const float4*)(src + 4);
    float xs[8] = {x0.x, x0.y, x0.z, x0.w, x1.x, x1.y, x1.z, x1.w};
    int kt = k >> 5, kc = k & 31;
    ushort* dh = (which < 3) ? qkvh : wdh;
    ushort* dl = (which < 3) ? qkvl : wdl;
    int ngbase = (which < 3) ? which * Dc + nl : nl;
#pragma unroll
    for (int j = 0; j < 8; ++j) {
        float x = xs[j];
        ushort hi = f2bf(x);
        ushort lo = f2bf(x - bf2f(hi));
        int ng = ngbase + j;
        int nt = ng >> 7, row = ng & 127;
        int off = (nt * NKT + kt) * 4096 + sw_us(row, kc);
        dh[off] = hi;
        dl[off] = lo;
    }
}

// ---------------- split-bf16 MFMA GEMM: C = A@B (+bias) --------------------
// MODE 0: bf16 out — q/k head-major [b,h,l,d], v TRANSPOSED [b,h,d,l].
// MODE 1: fp32 out plain [M,768].
template <int MODE>
__global__ __launch_bounds__(256) void gemm_split(
    const ushort* __restrict__ Ah, const ushort* __restrict__ Al,
    const ushort* __restrict__ Bh, const ushort* __restrict__ Bl,
    const float* __restrict__ b0, const float* __restrict__ b1,
    const float* __restrict__ b2,
    ushort* __restrict__ o0, ushort* __restrict__ o1, ushort* __restrict__ o2,
    float* __restrict__ of) {
    __shared__ uint4 lds4[4][512];   // Ah | Al | Bh | Bl, 8 KB each

    const int nt = blockIdx.x, mt = blockIdx.y;
    const int tid = threadIdx.x, w = tid >> 6, lane = tid & 63;
    const int wr = w >> 1, wc = w & 1, r = lane & 15, g = lane >> 4;

    const ushort* gsrc;
    if (w == 0)      gsrc = Ah + (size_t)mt * NKT * 4096;
    else if (w == 1) gsrc = Al + (size_t)mt * NKT * 4096;
    else if (w == 2) gsrc = Bh + (size_t)nt * NKT * 4096;
    else             gsrc = Bl + (size_t)nt * NKT * 4096;
    ushort* ldst = (ushort*)&lds4[w][0];

    f32x4 acc[4][4];
#pragma unroll
    for (int a = 0; a < 4; ++a)
#pragma unroll
        for (int b = 0; b < 4; ++b) acc[a][b] = (f32x4){0.f, 0.f, 0.f, 0.f};

    for (int kt = 0; kt < NKT; ++kt) {
        __syncthreads();
        const ushort* s = gsrc + kt * 4096 + lane * 8;
#pragma unroll
        for (int c = 0; c < 8; ++c)
            __builtin_amdgcn_global_load_lds((gvoid*)(s + c * 512),
                                             (svoid*)(ldst + c * 512), 16, 0, 0);
        __syncthreads();

        bf16x8 af[4][2];
#pragma unroll
        for (int mf = 0; mf < 4; ++mf) {
            int off = sw_us(wr * 64 + mf * 16 + r, g * 8);
            af[mf][0] = *(const bf16x8*)((const ushort*)&lds4[0][0] + off);
            af[mf][1] = *(const bf16x8*)((const ushort*)&lds4[1][0] + off);
        }
#pragma unroll
        for (int nf = 0; nf < 4; ++nf) {
            int off = sw_us(wc * 64 + nf * 16 + r, g * 8);
            bf16x8 bh = *(const bf16x8*)((const ushort*)&lds4[2][0] + off);
            bf16x8 bl = *(const bf16x8*)((const ushort*)&lds4[3][0] + off);
#pragma unroll
            for (int mf = 0; mf < 4; ++mf) {
                acc[mf][nf] = __builtin_amdgcn_mfma_f32_16x16x32_bf16(af[mf][0], bh, acc[mf][nf], 0, 0, 0);
                acc[mf][nf] = __builtin_amdgcn_mfma_f32_16x16x32_bf16(af[mf][0], bl, acc[mf][nf], 0, 0, 0);
                acc[mf][nf] = __builtin_amdgcn_mfma_f32_16x16x32_bf16(af[mf][1], bh, acc[mf][nf], 0, 0, 0);
            }
        }
    }

    if (MODE == 0) {
        const int which = nt / 6;
        const float* bias = which == 0 ? b0 : which == 1 ? b1 : b2;
        ushort* outp = which == 0 ? o0 : which == 1 ? o1 : o2;
        const int nbase = nt * 128 - which * Dc + wc * 64;
        if (which < 2) {
#pragma unroll
            for (int nf = 0; nf < 4; ++nf) {
                int nl = nbase + nf * 16 + r;
                float bb = bias[nl];
                int h = nl >> 6, d = nl & 63;
#pragma unroll
                for (int mf = 0; mf < 4; ++mf) {
                    int mbase = mt * 128 + wr * 64 + mf * 16 + g * 4;
#pragma unroll
                    for (int i = 0; i < 4; ++i) {
                        int m = mbase + i, bI = m >> 10, l = m & 1023;
                        outp[(((size_t)bI * Hc + h) * Lc + l) * HDc + d] =
                            f2bf(acc[mf][nf][i] + bb);
                    }
                }
            }
        } else {   // V: transposed [b, h, d, l], vectorized along l
#pragma unroll
            for (int nf = 0; nf < 4; ++nf) {
                int nl = nbase + nf * 16 + r;
                float bb = bias[nl];
                int h = nl >> 6, d = nl & 63;
#pragma unroll
                for (int mf = 0; mf < 4; ++mf) {
                    int mbase = mt * 128 + wr * 64 + mf * 16 + g * 4;
                    int bI = mbase >> 10, l = mbase & 1023;
                    ushort4 c;
                    c.x = f2bf(acc[mf][nf][0] + bb);
                    c.y = f2bf(acc[mf][nf][1] + bb);
                    c.z = f2bf(acc[mf][nf][2] + bb);
                    c.w = f2bf(acc[mf][nf][3] + bb);
                    *(ushort4*)&outp[((size_t)(bI * Hc + h) * HDc + d) * Lc + l] = c;
                }
            }
        }
    } else {
#pragma unroll
        for (int nf = 0; nf < 4; ++nf) {
            int n = nt * 128 + wc * 64 + nf * 16 + r;
            float bb = b0[n];
#pragma unroll
            for (int mf = 0; mf < 4; ++mf) {
                int mbase = mt * 128 + wr * 64 + mf * 16 + g * 4;
#pragma unroll
                for (int i = 0; i < 4; ++i) {
                    int m = mbase + i;
                    of[(size_t)m * Dc + n] = acc[mf][nf][i] + bb;
                }
            }
        }
    }
}

// ---------------- Wave-independent rel-pos attention (zero barriers) -------
// grid (64, H, B), 64 threads = 1 wave owning 16 query rows (strip).
// scores[l][r] = (q.k + q.E_j + k.E_j)/8, j = l-r+1023.
// K/V^T/E read directly from global (L2-resident); LDS is wave-private.
__global__ __launch_bounds__(64) void attn_mfma(
    const ushort* __restrict__ qg, const ushort* __restrict__ kg,
    const ushort* __restrict__ vtg, const ushort* __restrict__ Eb,
    ushort* __restrict__ ctxh, ushort* __restrict__ ctxl)
{
    const int b = blockIdx.z, h = blockIdx.y;
    const int l0s = blockIdx.x * 16;          // strip of 16 query rows
    const size_t bh = (size_t)(b * Hc + h) * Lc * HDc;
    const ushort* qh = qg + bh;
    const ushort* kh = kg + bh;
    const ushort* vth = vtg + bh;             // [d][l], row stride Lc

    __shared__ ushort sTq[16 * 92];           //  2944 B  QE skew table
    __shared__ ushort sTk[64 * 92];           // 11776 B  KE skew table
    __shared__ ushort sTp[16 * 72];           //  2304 B  P repack

    const int lane = threadIdx.x & 63;
    const int g = lane >> 4;                  // 0..3
    const int r = lane & 15;                  // 0..15

    bf16x8 qf0, qf1;
    {
        const ushort* qrow = qh + (size_t)(l0s + r) * 64;
        qf0 = *reinterpret_cast<const bf16x8*>(qrow + g * 8);
        qf1 = *reinterpret_cast<const bf16x8*>(qrow + 32 + g * 8);
    }

    f32x4 cacc[4];
#pragma unroll
    for (int cf = 0; cf < 4; ++cf) cacc[cf] = (f32x4){0.f, 0.f, 0.f, 0.f};
    float mrun[4], lrun[4];
#pragma unroll
    for (int i = 0; i < 4; ++i) { mrun[i] = -1e30f; lrun[i] = 0.f; }

    for (int r0 = 0; r0 < Lc; r0 += 64) {
        // ---- load K fragments (rows 16c+r of the key tile)
        bf16x8 kf[4][2];
#pragma unroll
        for (int c = 0; c < 4; ++c) {
            const ushort* krow = kh + (size_t)(r0 + 16 * c + r) * 64;
            kf[c][0] = *reinterpret_cast<const bf16x8*>(krow + g * 8);
            kf[c][1] = *reinterpret_cast<const bf16x8*>(krow + 32 + g * 8);
        }

        // ---- QK^T
        __builtin_amdgcn_s_setprio(1);
        f32x4 S[4];
#pragma unroll
        for (int cf = 0; cf < 4; ++cf) {
            f32x4 acc = (f32x4){0.f, 0.f, 0.f, 0.f};
            acc = __builtin_amdgcn_mfma_f32_16x16x32_bf16(qf0, kf[cf][0], acc, 0, 0, 0);
            acc = __builtin_amdgcn_mfma_f32_16x16x32_bf16(qf1, kf[cf][1], acc, 0, 0, 0);
            S[cf] = acc;
        }

        // ---- QE + KE over the 79-wide E band (5 col-fragments)
        // j = qr_g - kc_g + 1023 -> band rows jb0 + e, e = qr_l - kc_l + 63 in [0,78]
        const int jb0 = l0s - r0 + 960;       // in [0,1968]; rows jb0..jb0+79 valid (E padded to 2048)
#pragma unroll
        for (int cc = 0; cc < 5; ++cc) {
            const ushort* erow = Eb + (size_t)(jb0 + 16 * cc + r) * 64;
            bf16x8 e0 = *reinterpret_cast<const bf16x8*>(erow + g * 8);
            bf16x8 e1 = *reinterpret_cast<const bf16x8*>(erow + 32 + g * 8);
            f32x4 aq = (f32x4){0.f, 0.f, 0.f, 0.f};
            aq = __builtin_amdgcn_mfma_f32_16x16x32_bf16(qf0, e0, aq, 0, 0, 0);
            aq = __builtin_amdgcn_mfma_f32_16x16x32_bf16(qf1, e1, aq, 0, 0, 0);
#pragma unroll
            for (int i = 0; i < 4; ++i)
                sTq[(4 * g + i) * 92 + 16 * cc + r] = f2bf(aq[i]);
#pragma unroll
            for (int c = 0; c < 4; ++c) {
                f32x4 ak = (f32x4){0.f, 0.f, 0.f, 0.f};
                ak = __builtin_amdgcn_mfma_f32_16x16x32_bf16(kf[c][0], e0, ak, 0, 0, 0);
                ak = __builtin_amdgcn_mfma_f32_16x16x32_bf16(kf[c][1], e1, ak, 0, 0, 0);
#pragma unroll
                for (int i = 0; i < 4; ++i)
                    sTk[(16 * c + 4 * g + i) * 92 + 16 * cc + r] = f2bf(ak[i]);
            }
        }
        __builtin_amdgcn_s_setprio(0);

        // ---- assemble S + online softmax (rows 4g+i, cols 16cf+r)
        float p[4][4];
#pragma unroll
        for (int cf = 0; cf < 4; ++cf) {
#pragma unroll
            for (int i = 0; i < 4; ++i) {
                int qrl = 4 * g + i;
                int kcl = 16 * cf + r;
                int e = qrl - kcl + 63;       // 0..78
                p[cf][i] = (S[cf][i] + bf2f(sTq[qrl * 92 + e])
                                     + bf2f(sTk[kcl * 92 + e])) * 0.125f;
            }
        }
#pragma unroll
        for (int i = 0; i < 4; ++i) {
            float m0 = fmaxf(fmaxf(p[0][i], p[1][i]), fmaxf(p[2][i], p[3][i]));
#pragma unroll
            for (int off = 1; off < 16; off <<= 1) m0 = fmaxf(m0, __shfl_xor(m0, off));
            float mn = fmaxf(mrun[i], m0);
            float sc = __expf(mrun[i] - mn);
            mrun[i] = mn;
            float rsum = 0.f;
#pragma unroll
            for (int cf = 0; cf < 4; ++cf) {
                float e = __expf(p[cf][i] - mn);
                p[cf][i] = e;
                rsum += e;
            }
#pragma unroll
            for (int off = 1; off < 16; off <<= 1) rsum += __shfl_xor(rsum, off);
            lrun[i] = lrun[i] * sc + rsum;
#pragma unroll
            for (int cf = 0; cf < 4; ++cf) cacc[cf][i] *= sc;
        }

        // ---- repack P (C-frag -> A-frag) via private LDS
#pragma unroll
        for (int cf = 0; cf < 4; ++cf)
#pragma unroll
            for (int i = 0; i < 4; ++i)
                sTp[(4 * g + i) * 72 + 16 * cf + r] = f2bf(p[cf][i]);

        bf16x8 pf0 = *reinterpret_cast<const bf16x8*>(&sTp[r * 72 + g * 8]);
        bf16x8 pf1 = *reinterpret_cast<const bf16x8*>(&sTp[r * 72 + 32 + g * 8]);

        // ---- PV: V fragments direct from global V^T
        __builtin_amdgcn_s_setprio(1);
#pragma unroll
        for (int cf = 0; cf < 4; ++cf) {
            const ushort* vrow = vth + (size_t)(16 * cf + r) * Lc + r0;
            bf16x8 vf0 = *reinterpret_cast<const bf16x8*>(vrow + g * 8);
            bf16x8 vf1 = *reinterpret_cast<const bf16x8*>(vrow + 32 + g * 8);
            cacc[cf] = __builtin_amdgcn_mfma_f32_16x16x32_bf16(pf0, vf0, cacc[cf], 0, 0, 0);
            cacc[cf] = __builtin_amdgcn_mfma_f32_16x16x32_bf16(pf1, vf1, cacc[cf], 0, 0, 0);
        }
        __builtin_amdgcn_s_setprio(0);
    }

    // ---- epilogue: write ctx as swizzled hi/lo A-tiles for the output GEMM
    float rinv[4];
#pragma unroll
    for (int i = 0; i < 4; ++i) rinv[i] = 1.0f / lrun[i];
#pragma unroll
    for (int cf = 0; cf < 4; ++cf) {
#pragma unroll
        for (int i = 0; i < 4; ++i) {
            int qr = 4 * g + i;
            float val = cacc[cf][i] * rinv[i];
            ushort hi = f2bf(val);
            ushort lo = f2bf(val - bf2f(hi));
            int m = b * Lc + l0s + qr;
            int c = h * HDc + 16 * cf + r;
            int off = ((m >> 7) * NKT + (c >> 5)) * 4096 + sw_us(m & 127, c & 31);
            ctxh[off] = hi;
            ctxl[off] = lo;
        }
    }
}

extern "C" void kernel_launch(void* const* d_in, const int* in_sizes, int n_in,
                              void* d_out, int out_size, void* d_ws, size_t ws_size,
                              hipStream_t stream) {
    const float* hs = (const float*)d_in[0];
    const float* Wq = (const float*)d_in[1];
    const float* bq = (const float*)d_in[2];
    const float* Wk = (const float*)d_in[3];
    const float* bk = (const float*)d_in[4];
    const float* Wv = (const float*)d_in[5];
    const float* bv = (const float*)d_in[6];
    const float* Wd = (const float*)d_in[7];
    const float* bd = (const float*)d_in[8];
    const float* Eg = (const float*)d_in[9];

    const size_t N = (size_t)Bc * Lc * Dc;               // 3,145,728
    ushort* p = (ushort*)d_ws;
    ushort* qbf   = p;               p += N;
    ushort* kbf   = p;               p += N;
    ushort* vbf   = p;               p += N;             // V^T [b,h,d,l]
    ushort* hsh   = p;               p += N;             // aliased: ctx_hi after QKV
    ushort* hsl   = p;               p += N;             // aliased: ctx_lo
    ushort* wqkvh = p;               p += (size_t)2304 * 768;
    ushort* wqkvl = p;               p += (size_t)2304 * 768;
    ushort* Ebf   = p;               p += (size_t)2048 * HDc;   // padded to 2048 rows
    ushort* wdh   = p;               p += (size_t)768 * 768;
    ushort* wdl   = p;               p += (size_t)768 * 768;

    const int NE = (2 * 1024 - 1) * HDc;                 // 131,008
    const int NEP = 2048 * HDc;                          // 131,072 (padded)

    cvt_bf16_k<<<dim3(512), dim3(256), 0, stream>>>(Eg, Ebf, NE, NEP);
    prep_hs<<<dim3(1536), dim3(256), 0, stream>>>(hs, hsh, hsl);
    prep_w<<<dim3(1152), dim3(256), 0, stream>>>(Wq, Wk, Wv, Wd, wqkvh, wqkvl, wdh, wdl);

    gemm_split<0><<<dim3(18, 32), dim3(256), 0, stream>>>(
        hsh, hsl, wqkvh, wqkvl, bq, bk, bv, qbf, kbf, vbf, nullptr);

    attn_mfma<<<dim3(64, Hc, Bc), dim3(64), 0, stream>>>(
        qbf, kbf, vbf, Ebf, hsh, hsl);                   // ctx overwrites hs tiles

    gemm_split<1><<<dim3(6, 32), dim3(256), 0, stream>>>(
        hsh, hsl, wdh, wdl, bd, bd, bd, nullptr, nullptr, nullptr, (float*)d_out);
}

// Round 7
// 292.137 us; speedup vs baseline: 1.5295x; 1.5295x over previous
//
#include <hip/hip_runtime.h>
#include <hip/hip_bf16.h>
#include <math.h>

typedef __bf16 bf16x8 __attribute__((ext_vector_type(8)));
typedef float f32x4 __attribute__((ext_vector_type(4)));

#define AS1 __attribute__((address_space(1)))
#define AS3 __attribute__((address_space(3)))
typedef AS1 const void gvoid;
typedef AS3 void svoid;

namespace {
constexpr int Bc = 4, Lc = 1024, Dc = 768, Hc = 12, HDc = 64;
constexpr int NKT = 24;          // K tiles: 768 / 32
}

static __device__ __forceinline__ ushort f2bf(float f) {
    __hip_bfloat16 h = __float2bfloat16(f);
    return *reinterpret_cast<ushort*>(&h);
}
static __device__ __forceinline__ float bf2f(ushort u) {
    __hip_bfloat16 h;
    *reinterpret_cast<ushort*>(&h) = u;
    return __bfloat162float(h);
}

// offset (ushort units) within an 8 KB [128 rows][32 cols] bf16 tile,
// paired-row XOR swizzle (GEMM staging layout).
static __device__ __forceinline__ int sw_us(int row, int col) {
    int line = row >> 1;
    int slot = (((row & 1) << 2) + (col >> 3)) ^ (line & 7);
    return line * 64 + slot * 8 + (col & 7);
}

// offset (ushort units) in a [rows][64] bf16 tile, slot-XOR swizzled.
static __device__ __forceinline__ int o64(int row, int col) {
    return (row << 6) + ((((col >> 3) ^ (row & 7))) << 3) + (col & 7);
}

// ------- fp32 -> bf16 convert (dist_emb), zero-pad to 2048 rows ------------
__global__ void cvt_bf16_k(const float* __restrict__ in, ushort* __restrict__ out,
                           int n, int ntot) {
    int i = blockIdx.x * 256 + threadIdx.x;
    if (i < ntot) out[i] = (i < n) ? f2bf(in[i]) : (ushort)0;
}

// ---------------- hs [4096,768] fp32 -> tiled swizzled hi/lo ---------------
__global__ __launch_bounds__(256) void prep_hs(const float* __restrict__ hs,
                                               ushort* __restrict__ oh,
                                               ushort* __restrict__ ol) {
    int i = blockIdx.x * 256 + threadIdx.x;      // 4096*96
    int m = i / 96, c8 = i % 96;
    const float* src = hs + (size_t)m * Dc + c8 * 8;
    float4 x0 = *(const float4*)src;
    float4 x1 = *(const float4*)(src + 4);
    float xs[8] = {x0.x, x0.y, x0.z, x0.w, x1.x, x1.y, x1.z, x1.w};
    ushort hi[8], lo[8];
#pragma unroll
    for (int j = 0; j < 8; ++j) {
        hi[j] = f2bf(xs[j]);
        lo[j] = f2bf(xs[j] - bf2f(hi[j]));
    }
    int col = c8 * 8, kt = col >> 5, kc = col & 31;
    int mt = m >> 7, row = m & 127;
    int off = (mt * NKT + kt) * 4096 + sw_us(row, kc);
    *(uint4*)(oh + off) = *(uint4*)hi;
    *(uint4*)(ol + off) = *(uint4*)lo;
}

// ---------------- W^T tiles: Wq|Wk|Wv packed [2304 n], Wd [768 n] ----------
__global__ __launch_bounds__(256) void prep_w(
    const float* __restrict__ Wq, const float* __restrict__ Wk,
    const float* __restrict__ Wv, const float* __restrict__ Wd,
    ushort* __restrict__ qkvh, ushort* __restrict__ qkvl,
    ushort* __restrict__ wdh, ushort* __restrict__ wdl) {
    int i = blockIdx.x * 256 + threadIdx.x;      // 768*384
    int k = i / 384, n8 = i % 384;
    int which = n8 / 96, nl = (n8 % 96) * 8;
    const float* W = which == 0 ? Wq : which == 1 ? Wk : which == 2 ? Wv : Wd;
    const float* src = W + (size_t)k * Dc + nl;
    float4 x0 = *(const float4*)src;
    float4 x1 = *(const float4*)(src + 4);
    float xs[8] = {x0.x, x0.y, x0.z, x0.w, x1.x, x1.y, x1.z, x1.w};
    int kt = k >> 5, kc = k & 31;
    ushort* dh = (which < 3) ? qkvh : wdh;
    ushort* dl = (which < 3) ? qkvl : wdl;
    int ngbase = (which < 3) ? which * Dc + nl : nl;
#pragma unroll
    for (int j = 0; j < 8; ++j) {
        float x = xs[j];
        ushort hi = f2bf(x);
        ushort lo = f2bf(x - bf2f(hi));
        int ng = ngbase + j;
        int nt = ng >> 7, row = ng & 127;
        int off = (nt * NKT + kt) * 4096 + sw_us(row, kc);
        dh[off] = hi;
        dl[off] = lo;
    }
}

// ---------------- split-bf16 MFMA GEMM: C = A@B (+bias) --------------------
// MODE 0: bf16 out — q/k head-major [b,h,l,d], v TRANSPOSED [b,h,d,l].
// MODE 1: fp32 out plain [M,768].
template <int MODE>
__global__ __launch_bounds__(256) void gemm_split(
    const ushort* __restrict__ Ah, const ushort* __restrict__ Al,
    const ushort* __restrict__ Bh, const ushort* __restrict__ Bl,
    const float* __restrict__ b0, const float* __restrict__ b1,
    const float* __restrict__ b2,
    ushort* __restrict__ o0, ushort* __restrict__ o1, ushort* __restrict__ o2,
    float* __restrict__ of) {
    __shared__ uint4 lds4[4][512];   // Ah | Al | Bh | Bl, 8 KB each

    const int nt = blockIdx.x, mt = blockIdx.y;
    const int tid = threadIdx.x, w = tid >> 6, lane = tid & 63;
    const int wr = w >> 1, wc = w & 1, r = lane & 15, g = lane >> 4;

    const ushort* gsrc;
    if (w == 0)      gsrc = Ah + (size_t)mt * NKT * 4096;
    else if (w == 1) gsrc = Al + (size_t)mt * NKT * 4096;
    else if (w == 2) gsrc = Bh + (size_t)nt * NKT * 4096;
    else             gsrc = Bl + (size_t)nt * NKT * 4096;
    ushort* ldst = (ushort*)&lds4[w][0];

    f32x4 acc[4][4];
#pragma unroll
    for (int a = 0; a < 4; ++a)
#pragma unroll
        for (int b = 0; b < 4; ++b) acc[a][b] = (f32x4){0.f, 0.f, 0.f, 0.f};

    for (int kt = 0; kt < NKT; ++kt) {
        __syncthreads();
        const ushort* s = gsrc + kt * 4096 + lane * 8;
#pragma unroll
        for (int c = 0; c < 8; ++c)
            __builtin_amdgcn_global_load_lds((gvoid*)(s + c * 512),
                                             (svoid*)(ldst + c * 512), 16, 0, 0);
        __syncthreads();

        bf16x8 af[4][2];
#pragma unroll
        for (int mf = 0; mf < 4; ++mf) {
            int off = sw_us(wr * 64 + mf * 16 + r, g * 8);
            af[mf][0] = *(const bf16x8*)((const ushort*)&lds4[0][0] + off);
            af[mf][1] = *(const bf16x8*)((const ushort*)&lds4[1][0] + off);
        }
#pragma unroll
        for (int nf = 0; nf < 4; ++nf) {
            int off = sw_us(wc * 64 + nf * 16 + r, g * 8);
            bf16x8 bh = *(const bf16x8*)((const ushort*)&lds4[2][0] + off);
            bf16x8 bl = *(const bf16x8*)((const ushort*)&lds4[3][0] + off);
#pragma unroll
            for (int mf = 0; mf < 4; ++mf) {
                acc[mf][nf] = __builtin_amdgcn_mfma_f32_16x16x32_bf16(af[mf][0], bh, acc[mf][nf], 0, 0, 0);
                acc[mf][nf] = __builtin_amdgcn_mfma_f32_16x16x32_bf16(af[mf][0], bl, acc[mf][nf], 0, 0, 0);
                acc[mf][nf] = __builtin_amdgcn_mfma_f32_16x16x32_bf16(af[mf][1], bh, acc[mf][nf], 0, 0, 0);
            }
        }
    }

    if (MODE == 0) {
        const int which = nt / 6;
        const float* bias = which == 0 ? b0 : which == 1 ? b1 : b2;
        ushort* outp = which == 0 ? o0 : which == 1 ? o1 : o2;
        const int nbase = nt * 128 - which * Dc + wc * 64;
        if (which < 2) {
#pragma unroll
            for (int nf = 0; nf < 4; ++nf) {
                int nl = nbase + nf * 16 + r;
                float bb = bias[nl];
                int h = nl >> 6, d = nl & 63;
#pragma unroll
                for (int mf = 0; mf < 4; ++mf) {
                    int mbase = mt * 128 + wr * 64 + mf * 16 + g * 4;
#pragma unroll
                    for (int i = 0; i < 4; ++i) {
                        int m = mbase + i, bI = m >> 10, l = m & 1023;
                        outp[(((size_t)bI * Hc + h) * Lc + l) * HDc + d] =
                            f2bf(acc[mf][nf][i] + bb);
                    }
                }
            }
        } else {   // V: transposed [b, h, d, l], vectorized along l
#pragma unroll
            for (int nf = 0; nf < 4; ++nf) {
                int nl = nbase + nf * 16 + r;
                float bb = bias[nl];
                int h = nl >> 6, d = nl & 63;
#pragma unroll
                for (int mf = 0; mf < 4; ++mf) {
                    int mbase = mt * 128 + wr * 64 + mf * 16 + g * 4;
                    int bI = mbase >> 10, l = mbase & 1023;
                    ushort4 c;
                    c.x = f2bf(acc[mf][nf][0] + bb);
                    c.y = f2bf(acc[mf][nf][1] + bb);
                    c.z = f2bf(acc[mf][nf][2] + bb);
                    c.w = f2bf(acc[mf][nf][3] + bb);
                    *(ushort4*)&outp[((size_t)(bI * Hc + h) * HDc + d) * Lc + l] = c;
                }
            }
        }
    } else {
#pragma unroll
        for (int nf = 0; nf < 4; ++nf) {
            int n = nt * 128 + wc * 64 + nf * 16 + r;
            float bb = b0[n];
#pragma unroll
            for (int mf = 0; mf < 4; ++mf) {
                int mbase = mt * 128 + wr * 64 + mf * 16 + g * 4;
#pragma unroll
                for (int i = 0; i < 4; ++i) {
                    int m = mbase + i;
                    of[(size_t)m * Dc + n] = acc[mf][nf][i] + bb;
                }
            }
        }
    }
}

// ---------------- Fused relative-position attention (MFMA) -----------------
// R5 skeleton (4 waves, 4 barriers) + compact tables + slot-XOR swizzle.
// LDS 50688 B -> 3 blocks/CU; grid 768 = exactly 3 blocks/CU (no tail).
// scores[l][r] = (q.k + q.E_j + k.E_j)/8, j = l-r+1023.
// Tables: QEc[qr][63-kc] = QE[qr][qr-kc+63]; KEc[kc][qr] = KE[kc][qr-kc+63].
__global__ __launch_bounds__(256, 3) void attn_mfma(
    const ushort* __restrict__ qg, const ushort* __restrict__ kg,
    const ushort* __restrict__ vtg, const ushort* __restrict__ Eb,
    ushort* __restrict__ ctxh, ushort* __restrict__ ctxl)
{
    const int b = blockIdx.z, h = blockIdx.y;
    const int l0 = blockIdx.x * 64;
    const size_t bh = (size_t)(b * Hc + h) * Lc * HDc;
    const ushort* qh = qg + bh;
    const ushort* kh = kg + bh;
    const ushort* vth = vtg + bh;     // [d][l], row stride Lc

    __shared__ ushort sK[64 * 64];    //  8192 B, swizzled
    __shared__ ushort sVt[64 * 64];   //  8192 B, swizzled [dim][key]
    __shared__ ushort sE[128 * 64];   // 16384 B, swizzled; rows 0..63 reused as P
    __shared__ ushort sQE[64 * 70];   //  8960 B  compact QE table
    __shared__ ushort sKE[64 * 70];   //  8960 B  compact KE table

    const int tid = threadIdx.x;
    const int lane = tid & 63;
    const int w = tid >> 6;           // wave, strip rows 16w..16w+15
    const int g = lane >> 4;
    const int r = lane & 15;

    bf16x8 qf0, qf1;
    {
        const ushort* qrow = qh + (size_t)(l0 + 16 * w + r) * 64;
        qf0 = *reinterpret_cast<const bf16x8*>(qrow + g * 8);
        qf1 = *reinterpret_cast<const bf16x8*>(qrow + 32 + g * 8);
    }

    f32x4 cacc[4];
#pragma unroll
    for (int cf = 0; cf < 4; ++cf) cacc[cf] = (f32x4){0.f, 0.f, 0.f, 0.f};
    float mrun[4], lrun[4];
#pragma unroll
    for (int i = 0; i < 4; ++i) { mrun[i] = -1e30f; lrun[i] = 0.f; }

    for (int r0 = 0; r0 < Lc; r0 += 64) {
        __syncthreads();                       // D -> A
        // ---- phase A: stage K, V^T (swizzled), E band (swizzled)
#pragma unroll
        for (int i = 0; i < 2; ++i) {
            int idx = tid + i * 256;
            int row = idx >> 3, seg = idx & 7;
            int d = (row << 6) + ((seg ^ (row & 7)) << 3);
            *reinterpret_cast<uint4*>(&sK[d]) =
                *reinterpret_cast<const uint4*>(kh + (size_t)(r0 + row) * 64 + seg * 8);
            *reinterpret_cast<uint4*>(&sVt[d]) =
                *reinterpret_cast<const uint4*>(vth + (size_t)row * Lc + r0 + seg * 8);
        }
        const int jb = l0 - r0 + 960;          // rows jb..jb+126 valid in E
#pragma unroll
        for (int c = tid; c < 1024; c += 256) {
            int row = c >> 3, seg = c & 7;
            uint4 val;
            if (row < 127)
                val = *reinterpret_cast<const uint4*>(Eb + (size_t)(jb + row) * 64 + seg * 8);
            else
                val = make_uint4(0, 0, 0, 0);
            *reinterpret_cast<uint4*>(&sE[(row << 6) + ((seg ^ (row & 7)) << 3)]) = val;
        }
        __syncthreads();                       // A -> B

        // ---- phase B: QK^T + compact QE/KE tables (5 fragments each)
        __builtin_amdgcn_s_setprio(1);
        f32x4 S[4];
#pragma unroll
        for (int cf = 0; cf < 4; ++cf) {
            f32x4 acc = (f32x4){0.f, 0.f, 0.f, 0.f};
            bf16x8 kf0 = *reinterpret_cast<const bf16x8*>(&sK[o64(16 * cf + r, g * 8)]);
            bf16x8 kf1 = *reinterpret_cast<const bf16x8*>(&sK[o64(16 * cf + r, 32 + g * 8)]);
            acc = __builtin_amdgcn_mfma_f32_16x16x32_bf16(qf0, kf0, acc, 0, 0, 0);
            acc = __builtin_amdgcn_mfma_f32_16x16x32_bf16(qf1, kf1, acc, 0, 0, 0);
            S[cf] = acc;
        }
        bf16x8 kaf0 = *reinterpret_cast<const bf16x8*>(&sK[o64(16 * w + r, g * 8)]);
        bf16x8 kaf1 = *reinterpret_cast<const bf16x8*>(&sK[o64(16 * w + r, 32 + g * 8)]);
#pragma unroll
        for (int cc = 0; cc < 5; ++cc) {
            {   // QE: E rows 16(w+cc)+r
                int er = 16 * (w + cc) + r;
                bf16x8 e0 = *reinterpret_cast<const bf16x8*>(&sE[o64(er, g * 8)]);
                bf16x8 e1 = *reinterpret_cast<const bf16x8*>(&sE[o64(er, 32 + g * 8)]);
                f32x4 aq = (f32x4){0.f, 0.f, 0.f, 0.f};
                aq = __builtin_amdgcn_mfma_f32_16x16x32_bf16(qf0, e0, aq, 0, 0, 0);
                aq = __builtin_amdgcn_mfma_f32_16x16x32_bf16(qf1, e1, aq, 0, 0, 0);
#pragma unroll
                for (int i = 0; i < 4; ++i) {
                    int lc = 16 * cc + r - 4 * g - i;          // = j - qr
                    if ((unsigned)lc < 64u)
                        sQE[(16 * w + 4 * g + i) * 70 + lc] = f2bf(aq[i]);
                }
            }
            {   // KE: E rows 16(3-w+cc)+r
                int er = 16 * (3 - w + cc) + r;
                bf16x8 e0 = *reinterpret_cast<const bf16x8*>(&sE[o64(er, g * 8)]);
                bf16x8 e1 = *reinterpret_cast<const bf16x8*>(&sE[o64(er, 32 + g * 8)]);
                f32x4 ak = (f32x4){0.f, 0.f, 0.f, 0.f};
                ak = __builtin_amdgcn_mfma_f32_16x16x32_bf16(kaf0, e0, ak, 0, 0, 0);
                ak = __builtin_amdgcn_mfma_f32_16x16x32_bf16(kaf1, e1, ak, 0, 0, 0);
#pragma unroll
                for (int i = 0; i < 4; ++i) {
                    int lc = 16 * cc + r + 4 * g + i - 15;     // = qr = j + kc - 63
                    if ((unsigned)lc < 64u)
                        sKE[(16 * w + 4 * g + i) * 70 + lc] = f2bf(ak[i]);
                }
            }
        }
        __builtin_amdgcn_s_setprio(0);
        __syncthreads();                       // B -> C (E consumed, tables ready)

        // ---- phase C: gather + online softmax; write P over E rows 0..63
        float p[4][4];
#pragma unroll
        for (int cf = 0; cf < 4; ++cf) {
#pragma unroll
            for (int i = 0; i < 4; ++i) {
                int qr = 16 * w + 4 * g + i;
                int kc = 16 * cf + r;
                p[cf][i] = (S[cf][i] + bf2f(sQE[qr * 70 + 63 - kc])
                                     + bf2f(sKE[kc * 70 + qr])) * 0.125f;
            }
        }
#pragma unroll
        for (int i = 0; i < 4; ++i) {
            float m0 = fmaxf(fmaxf(p[0][i], p[1][i]), fmaxf(p[2][i], p[3][i]));
#pragma unroll
            for (int off = 1; off < 16; off <<= 1) m0 = fmaxf(m0, __shfl_xor(m0, off));
            float mn = fmaxf(mrun[i], m0);
            float sc = __expf(mrun[i] - mn);
            mrun[i] = mn;
            float rsum = 0.f;
#pragma unroll
            for (int cf = 0; cf < 4; ++cf) {
                float e = __expf(p[cf][i] - mn);
                p[cf][i] = e;
                rsum += e;
            }
#pragma unroll
            for (int off = 1; off < 16; off <<= 1) rsum += __shfl_xor(rsum, off);
            lrun[i] = lrun[i] * sc + rsum;
#pragma unroll
            for (int cf = 0; cf < 4; ++cf) cacc[cf][i] *= sc;
        }
#pragma unroll
        for (int cf = 0; cf < 4; ++cf)
#pragma unroll
            for (int i = 0; i < 4; ++i)
                sE[o64(16 * w + 4 * g + i, 16 * cf + r)] = f2bf(p[cf][i]);
        __syncthreads();                       // C -> D

        // ---- phase D: PV
        __builtin_amdgcn_s_setprio(1);
        bf16x8 pf0 = *reinterpret_cast<const bf16x8*>(&sE[o64(16 * w + r, g * 8)]);
        bf16x8 pf1 = *reinterpret_cast<const bf16x8*>(&sE[o64(16 * w + r, 32 + g * 8)]);
#pragma unroll
        for (int cf = 0; cf < 4; ++cf) {
            bf16x8 vf0 = *reinterpret_cast<const bf16x8*>(&sVt[o64(16 * cf + r, g * 8)]);
            bf16x8 vf1 = *reinterpret_cast<const bf16x8*>(&sVt[o64(16 * cf + r, 32 + g * 8)]);
            cacc[cf] = __builtin_amdgcn_mfma_f32_16x16x32_bf16(pf0, vf0, cacc[cf], 0, 0, 0);
            cacc[cf] = __builtin_amdgcn_mfma_f32_16x16x32_bf16(pf1, vf1, cacc[cf], 0, 0, 0);
        }
        __builtin_amdgcn_s_setprio(0);
    }

    // ---- epilogue: write ctx as swizzled hi/lo A-tiles for the output GEMM
    float rinv[4];
#pragma unroll
    for (int i = 0; i < 4; ++i) rinv[i] = 1.0f / lrun[i];
#pragma unroll
    for (int cf = 0; cf < 4; ++cf) {
#pragma unroll
        for (int i = 0; i < 4; ++i) {
            int qr = 16 * w + 4 * g + i;
            float val = cacc[cf][i] * rinv[i];
            ushort hi = f2bf(val);
            ushort lo = f2bf(val - bf2f(hi));
            int m = b * Lc + l0 + qr;
            int c = h * HDc + 16 * cf + r;
            int off = ((m >> 7) * NKT + (c >> 5)) * 4096 + sw_us(m & 127, c & 31);
            ctxh[off] = hi;
            ctxl[off] = lo;
        }
    }
}

extern "C" void kernel_launch(void* const* d_in, const int* in_sizes, int n_in,
                              void* d_out, int out_size, void* d_ws, size_t ws_size,
                              hipStream_t stream) {
    const float* hs = (const float*)d_in[0];
    const float* Wq = (const float*)d_in[1];
    const float* bq = (const float*)d_in[2];
    const float* Wk = (const float*)d_in[3];
    const float* bk = (const float*)d_in[4];
    const float* Wv = (const float*)d_in[5];
    const float* bv = (const float*)d_in[6];
    const float* Wd = (const float*)d_in[7];
    const float* bd = (const float*)d_in[8];
    const float* Eg = (const float*)d_in[9];

    const size_t N = (size_t)Bc * Lc * Dc;               // 3,145,728
    ushort* p = (ushort*)d_ws;
    ushort* qbf   = p;               p += N;
    ushort* kbf   = p;               p += N;
    ushort* vbf   = p;               p += N;             // V^T [b,h,d,l]
    ushort* hsh   = p;               p += N;             // aliased: ctx_hi after QKV
    ushort* hsl   = p;               p += N;             // aliased: ctx_lo
    ushort* wqkvh = p;               p += (size_t)2304 * 768;
    ushort* wqkvl = p;               p += (size_t)2304 * 768;
    ushort* Ebf   = p;               p += (size_t)2048 * HDc;   // padded to 2048 rows
    ushort* wdh   = p;               p += (size_t)768 * 768;
    ushort* wdl   = p;               p += (size_t)768 * 768;

    const int NE = (2 * 1024 - 1) * HDc;                 // 131,008
    const int NEP = 2048 * HDc;                          // 131,072 (padded)

    cvt_bf16_k<<<dim3(512), dim3(256), 0, stream>>>(Eg, Ebf, NE, NEP);
    prep_hs<<<dim3(1536), dim3(256), 0, stream>>>(hs, hsh, hsl);
    prep_w<<<dim3(1152), dim3(256), 0, stream>>>(Wq, Wk, Wv, Wd, wqkvh, wqkvl, wdh, wdl);

    gemm_split<0><<<dim3(18, 32), dim3(256), 0, stream>>>(
        hsh, hsl, wqkvh, wqkvl, bq, bk, bv, qbf, kbf, vbf, nullptr);

    attn_mfma<<<dim3(16, Hc, Bc), dim3(256), 0, stream>>>(
        qbf, kbf, vbf, Ebf, hsh, hsl);                   // ctx overwrites hs tiles

    gemm_split<1><<<dim3(6, 32), dim3(256), 0, stream>>>(
        hsh, hsl, wdh, wdl, bd, bd, bd, nullptr, nullptr, nullptr, (float*)d_out);
}

// Round 8
// 251.259 us; speedup vs baseline: 1.7784x; 1.1627x over previous
//
#include <hip/hip_runtime.h>
#include <hip/hip_bf16.h>
#include <math.h>

typedef __bf16 bf16x8 __attribute__((ext_vector_type(8)));
typedef float f32x4 __attribute__((ext_vector_type(4)));

#define AS1 __attribute__((address_space(1)))
#define AS3 __attribute__((address_space(3)))
typedef AS1 const void gvoid;
typedef AS3 void svoid;

namespace {
constexpr int Bc = 4, Lc = 1024, Dc = 768, Hc = 12, HDc = 64;
constexpr int NKT = 24;          // K tiles: 768 / 32
}

static __device__ __forceinline__ ushort f2bf(float f) {
    __hip_bfloat16 h = __float2bfloat16(f);
    return *reinterpret_cast<ushort*>(&h);
}
static __device__ __forceinline__ float bf2f(ushort u) {
    __hip_bfloat16 h;
    *reinterpret_cast<ushort*>(&h) = u;
    return __bfloat162float(h);
}

// offset (ushort units) within an 8 KB [128 rows][32 cols] bf16 tile,
// paired-row XOR swizzle (GEMM staging layout).
static __device__ __forceinline__ int sw_us(int row, int col) {
    int line = row >> 1;
    int slot = (((row & 1) << 2) + (col >> 3)) ^ (line & 7);
    return line * 64 + slot * 8 + (col & 7);
}

// offset (ushort units) in a [rows][64] bf16 tile, slot-XOR swizzled.
static __device__ __forceinline__ int o64(int row, int col) {
    return (row << 6) + ((((col >> 3) ^ (row & 7))) << 3) + (col & 7);
}

// ------- fp32 -> bf16 convert (dist_emb), zero-pad to 2048 rows ------------
__global__ void cvt_bf16_k(const float* __restrict__ in, ushort* __restrict__ out,
                           int n, int ntot) {
    int i = blockIdx.x * 256 + threadIdx.x;
    if (i < ntot) out[i] = (i < n) ? f2bf(in[i]) : (ushort)0;
}

// ---------------- hs [4096,768] fp32 -> tiled swizzled hi (bf16) -----------
__global__ __launch_bounds__(256) void prep_hs(const float* __restrict__ hs,
                                               ushort* __restrict__ oh) {
    int i = blockIdx.x * 256 + threadIdx.x;      // 4096*96
    int m = i / 96, c8 = i % 96;
    const float* src = hs + (size_t)m * Dc + c8 * 8;
    float4 x0 = *(const float4*)src;
    float4 x1 = *(const float4*)(src + 4);
    float xs[8] = {x0.x, x0.y, x0.z, x0.w, x1.x, x1.y, x1.z, x1.w};
    ushort hi[8];
#pragma unroll
    for (int j = 0; j < 8; ++j) hi[j] = f2bf(xs[j]);
    int col = c8 * 8, kt = col >> 5, kc = col & 31;
    int mt = m >> 7, row = m & 127;
    int off = (mt * NKT + kt) * 4096 + sw_us(row, kc);
    *(uint4*)(oh + off) = *(uint4*)hi;
}

// ------- W^T tiles: Wq|Wk|Wv packed [2304 n] hi-only; Wd [768 n] hi+lo -----
__global__ __launch_bounds__(256) void prep_w(
    const float* __restrict__ Wq, const float* __restrict__ Wk,
    const float* __restrict__ Wv, const float* __restrict__ Wd,
    ushort* __restrict__ qkvh,
    ushort* __restrict__ wdh, ushort* __restrict__ wdl) {
    int i = blockIdx.x * 256 + threadIdx.x;      // 768*384
    int k = i / 384, n8 = i % 384;
    int which = n8 / 96, nl = (n8 % 96) * 8;
    const float* W = which == 0 ? Wq : which == 1 ? Wk : which == 2 ? Wv : Wd;
    const float* src = W + (size_t)k * Dc + nl;
    float4 x0 = *(const float4*)src;
    float4 x1 = *(const float4*)(src + 4);
    float xs[8] = {x0.x, x0.y, x0.z, x0.w, x1.x, x1.y, x1.z, x1.w};
    int kt = k >> 5, kc = k & 31;
    ushort* dh = (which < 3) ? qkvh : wdh;
    int ngbase = (which < 3) ? which * Dc + nl : nl;
#pragma unroll
    for (int j = 0; j < 8; ++j) {
        float x = xs[j];
        ushort hi = f2bf(x);
        int ng = ngbase + j;
        int nt = ng >> 7, row = ng & 127;
        int off = (nt * NKT + kt) * 4096 + sw_us(row, kc);
        dh[off] = hi;
        if (which == 3) wdl[off] = f2bf(x - bf2f(hi));
    }
}

// ---------------- pure-bf16 MFMA GEMM: QKV projection ----------------------
// A tiles [mt][kt][128m][32k], B tiles [nt][kt][128n][32k] (pre-swizzled).
// out: q/k head-major [b,h,l,d] bf16, v TRANSPOSED [b,h,d,l] bf16.
__global__ __launch_bounds__(256) void gemm_qkv(
    const ushort* __restrict__ Ah, const ushort* __restrict__ Bh,
    const float* __restrict__ b0, const float* __restrict__ b1,
    const float* __restrict__ b2,
    ushort* __restrict__ o0, ushort* __restrict__ o1, ushort* __restrict__ o2) {
    __shared__ uint4 lds4[2][512];   // Ah | Bh, 8 KB each

    const int nt = blockIdx.x, mt = blockIdx.y;
    const int tid = threadIdx.x, w = tid >> 6, lane = tid & 63;
    const int wr = w >> 1, wc = w & 1, r = lane & 15, g = lane >> 4;

    // wave w stages a 4 KB half-tile: w0/w1 -> Ah halves, w2/w3 -> Bh halves
    const ushort* gsrc = ((w < 2) ? Ah + (size_t)mt * NKT * 4096
                                  : Bh + (size_t)nt * NKT * 4096) + (w & 1) * 2048;
    ushort* ldst = (ushort*)&lds4[w >> 1][0] + (w & 1) * 2048;

    f32x4 acc[4][4];
#pragma unroll
    for (int a = 0; a < 4; ++a)
#pragma unroll
        for (int b = 0; b < 4; ++b) acc[a][b] = (f32x4){0.f, 0.f, 0.f, 0.f};

    for (int kt = 0; kt < NKT; ++kt) {
        __syncthreads();
        const ushort* s = gsrc + kt * 4096 + lane * 8;
#pragma unroll
        for (int c = 0; c < 4; ++c)
            __builtin_amdgcn_global_load_lds((gvoid*)(s + c * 512),
                                             (svoid*)(ldst + c * 512), 16, 0, 0);
        __syncthreads();

        bf16x8 af[4];
#pragma unroll
        for (int mf = 0; mf < 4; ++mf)
            af[mf] = *(const bf16x8*)((const ushort*)&lds4[0][0] +
                                      sw_us(wr * 64 + mf * 16 + r, g * 8));
#pragma unroll
        for (int nf = 0; nf < 4; ++nf) {
            bf16x8 bf = *(const bf16x8*)((const ushort*)&lds4[1][0] +
                                         sw_us(wc * 64 + nf * 16 + r, g * 8));
#pragma unroll
            for (int mf = 0; mf < 4; ++mf)
                acc[mf][nf] = __builtin_amdgcn_mfma_f32_16x16x32_bf16(af[mf], bf, acc[mf][nf], 0, 0, 0);
        }
    }

    const int which = nt / 6;
    const float* bias = which == 0 ? b0 : which == 1 ? b1 : b2;
    ushort* outp = which == 0 ? o0 : which == 1 ? o1 : o2;
    const int nbase = nt * 128 - which * Dc + wc * 64;
    if (which < 2) {
#pragma unroll
        for (int nf = 0; nf < 4; ++nf) {
            int nl = nbase + nf * 16 + r;
            float bb = bias[nl];
            int h = nl >> 6, d = nl & 63;
#pragma unroll
            for (int mf = 0; mf < 4; ++mf) {
                int mbase = mt * 128 + wr * 64 + mf * 16 + g * 4;
#pragma unroll
                for (int i = 0; i < 4; ++i) {
                    int m = mbase + i, bI = m >> 10, l = m & 1023;
                    outp[(((size_t)bI * Hc + h) * Lc + l) * HDc + d] =
                        f2bf(acc[mf][nf][i] + bb);
                }
            }
        }
    } else {   // V: transposed [b, h, d, l], vectorized along l
#pragma unroll
        for (int nf = 0; nf < 4; ++nf) {
            int nl = nbase + nf * 16 + r;
            float bb = bias[nl];
            int h = nl >> 6, d = nl & 63;
#pragma unroll
            for (int mf = 0; mf < 4; ++mf) {
                int mbase = mt * 128 + wr * 64 + mf * 16 + g * 4;
                int bI = mbase >> 10, l = mbase & 1023;
                ushort4 c;
                c.x = f2bf(acc[mf][nf][0] + bb);
                c.y = f2bf(acc[mf][nf][1] + bb);
                c.z = f2bf(acc[mf][nf][2] + bb);
                c.w = f2bf(acc[mf][nf][3] + bb);
                *(ushort4*)&outp[((size_t)(bI * Hc + h) * HDc + d) * Lc + l] = c;
            }
        }
    }
}

// ---------------- split-bf16 MFMA GEMM: out-proj (fp32 out) ----------------
__global__ __launch_bounds__(256) void gemm_split(
    const ushort* __restrict__ Ah, const ushort* __restrict__ Al,
    const ushort* __restrict__ Bh, const ushort* __restrict__ Bl,
    const float* __restrict__ b0,
    float* __restrict__ of) {
    __shared__ uint4 lds4[4][512];   // Ah | Al | Bh | Bl, 8 KB each

    const int nt = blockIdx.x, mt = blockIdx.y;
    const int tid = threadIdx.x, w = tid >> 6, lane = tid & 63;
    const int wr = w >> 1, wc = w & 1, r = lane & 15, g = lane >> 4;

    const ushort* gsrc;
    if (w == 0)      gsrc = Ah + (size_t)mt * NKT * 4096;
    else if (w == 1) gsrc = Al + (size_t)mt * NKT * 4096;
    else if (w == 2) gsrc = Bh + (size_t)nt * NKT * 4096;
    else             gsrc = Bl + (size_t)nt * NKT * 4096;
    ushort* ldst = (ushort*)&lds4[w][0];

    f32x4 acc[4][4];
#pragma unroll
    for (int a = 0; a < 4; ++a)
#pragma unroll
        for (int b = 0; b < 4; ++b) acc[a][b] = (f32x4){0.f, 0.f, 0.f, 0.f};

    for (int kt = 0; kt < NKT; ++kt) {
        __syncthreads();
        const ushort* s = gsrc + kt * 4096 + lane * 8;
#pragma unroll
        for (int c = 0; c < 8; ++c)
            __builtin_amdgcn_global_load_lds((gvoid*)(s + c * 512),
                                             (svoid*)(ldst + c * 512), 16, 0, 0);
        __syncthreads();

        bf16x8 af[4][2];
#pragma unroll
        for (int mf = 0; mf < 4; ++mf) {
            int off = sw_us(wr * 64 + mf * 16 + r, g * 8);
            af[mf][0] = *(const bf16x8*)((const ushort*)&lds4[0][0] + off);
            af[mf][1] = *(const bf16x8*)((const ushort*)&lds4[1][0] + off);
        }
#pragma unroll
        for (int nf = 0; nf < 4; ++nf) {
            int off = sw_us(wc * 64 + nf * 16 + r, g * 8);
            bf16x8 bh = *(const bf16x8*)((const ushort*)&lds4[2][0] + off);
            bf16x8 bl = *(const bf16x8*)((const ushort*)&lds4[3][0] + off);
#pragma unroll
            for (int mf = 0; mf < 4; ++mf) {
                acc[mf][nf] = __builtin_amdgcn_mfma_f32_16x16x32_bf16(af[mf][0], bh, acc[mf][nf], 0, 0, 0);
                acc[mf][nf] = __builtin_amdgcn_mfma_f32_16x16x32_bf16(af[mf][0], bl, acc[mf][nf], 0, 0, 0);
                acc[mf][nf] = __builtin_amdgcn_mfma_f32_16x16x32_bf16(af[mf][1], bh, acc[mf][nf], 0, 0, 0);
            }
        }
    }

#pragma unroll
    for (int nf = 0; nf < 4; ++nf) {
        int n = nt * 128 + wc * 64 + nf * 16 + r;
        float bb = b0[n];
#pragma unroll
        for (int mf = 0; mf < 4; ++mf) {
            int mbase = mt * 128 + wr * 64 + mf * 16 + g * 4;
#pragma unroll
            for (int i = 0; i < 4; ++i) {
                int m = mbase + i;
                of[(size_t)m * Dc + n] = acc[mf][nf][i] + bb;
            }
        }
    }
}

// ---------------- Fused relative-position attention (MFMA) -----------------
// R7 structure (frozen): 4 waves, 4 barriers, compact tables, slot-XOR
// swizzle, LDS 50688 B -> 3 blocks/CU; grid 768 = exactly 3 blocks/CU.
__global__ __launch_bounds__(256, 3) void attn_mfma(
    const ushort* __restrict__ qg, const ushort* __restrict__ kg,
    const ushort* __restrict__ vtg, const ushort* __restrict__ Eb,
    ushort* __restrict__ ctxh, ushort* __restrict__ ctxl)
{
    const int b = blockIdx.z, h = blockIdx.y;
    const int l0 = blockIdx.x * 64;
    const size_t bh = (size_t)(b * Hc + h) * Lc * HDc;
    const ushort* qh = qg + bh;
    const ushort* kh = kg + bh;
    const ushort* vth = vtg + bh;     // [d][l], row stride Lc

    __shared__ ushort sK[64 * 64];    //  8192 B, swizzled
    __shared__ ushort sVt[64 * 64];   //  8192 B, swizzled [dim][key]
    __shared__ ushort sE[128 * 64];   // 16384 B, swizzled; rows 0..63 reused as P
    __shared__ ushort sQE[64 * 70];   //  8960 B  compact QE table
    __shared__ ushort sKE[64 * 70];   //  8960 B  compact KE table

    const int tid = threadIdx.x;
    const int lane = tid & 63;
    const int w = tid >> 6;           // wave, strip rows 16w..16w+15
    const int g = lane >> 4;
    const int r = lane & 15;

    bf16x8 qf0, qf1;
    {
        const ushort* qrow = qh + (size_t)(l0 + 16 * w + r) * 64;
        qf0 = *reinterpret_cast<const bf16x8*>(qrow + g * 8);
        qf1 = *reinterpret_cast<const bf16x8*>(qrow + 32 + g * 8);
    }

    f32x4 cacc[4];
#pragma unroll
    for (int cf = 0; cf < 4; ++cf) cacc[cf] = (f32x4){0.f, 0.f, 0.f, 0.f};
    float mrun[4], lrun[4];
#pragma unroll
    for (int i = 0; i < 4; ++i) { mrun[i] = -1e30f; lrun[i] = 0.f; }

    for (int r0 = 0; r0 < Lc; r0 += 64) {
        __syncthreads();                       // D -> A
        // ---- phase A: stage K, V^T (swizzled), E band (swizzled)
#pragma unroll
        for (int i = 0; i < 2; ++i) {
            int idx = tid + i * 256;
            int row = idx >> 3, seg = idx & 7;
            int d = (row << 6) + ((seg ^ (row & 7)) << 3);
            *reinterpret_cast<uint4*>(&sK[d]) =
                *reinterpret_cast<const uint4*>(kh + (size_t)(r0 + row) * 64 + seg * 8);
            *reinterpret_cast<uint4*>(&sVt[d]) =
                *reinterpret_cast<const uint4*>(vth + (size_t)row * Lc + r0 + seg * 8);
        }
        const int jb = l0 - r0 + 960;          // rows jb..jb+126 valid in E
#pragma unroll
        for (int c = tid; c < 1024; c += 256) {
            int row = c >> 3, seg = c & 7;
            uint4 val;
            if (row < 127)
                val = *reinterpret_cast<const uint4*>(Eb + (size_t)(jb + row) * 64 + seg * 8);
            else
                val = make_uint4(0, 0, 0, 0);
            *reinterpret_cast<uint4*>(&sE[(row << 6) + ((seg ^ (row & 7)) << 3)]) = val;
        }
        __syncthreads();                       // A -> B

        // ---- phase B: QK^T + compact QE/KE tables (5 fragments each)
        __builtin_amdgcn_s_setprio(1);
        f32x4 S[4];
#pragma unroll
        for (int cf = 0; cf < 4; ++cf) {
            f32x4 acc = (f32x4){0.f, 0.f, 0.f, 0.f};
            bf16x8 kf0 = *reinterpret_cast<const bf16x8*>(&sK[o64(16 * cf + r, g * 8)]);
            bf16x8 kf1 = *reinterpret_cast<const bf16x8*>(&sK[o64(16 * cf + r, 32 + g * 8)]);
            acc = __builtin_amdgcn_mfma_f32_16x16x32_bf16(qf0, kf0, acc, 0, 0, 0);
            acc = __builtin_amdgcn_mfma_f32_16x16x32_bf16(qf1, kf1, acc, 0, 0, 0);
            S[cf] = acc;
        }
        bf16x8 kaf0 = *reinterpret_cast<const bf16x8*>(&sK[o64(16 * w + r, g * 8)]);
        bf16x8 kaf1 = *reinterpret_cast<const bf16x8*>(&sK[o64(16 * w + r, 32 + g * 8)]);
#pragma unroll
        for (int cc = 0; cc < 5; ++cc) {
            {   // QE: E rows 16(w+cc)+r
                int er = 16 * (w + cc) + r;
                bf16x8 e0 = *reinterpret_cast<const bf16x8*>(&sE[o64(er, g * 8)]);
                bf16x8 e1 = *reinterpret_cast<const bf16x8*>(&sE[o64(er, 32 + g * 8)]);
                f32x4 aq = (f32x4){0.f, 0.f, 0.f, 0.f};
                aq = __builtin_amdgcn_mfma_f32_16x16x32_bf16(qf0, e0, aq, 0, 0, 0);
                aq = __builtin_amdgcn_mfma_f32_16x16x32_bf16(qf1, e1, aq, 0, 0, 0);
#pragma unroll
                for (int i = 0; i < 4; ++i) {
                    int lc = 16 * cc + r - 4 * g - i;          // = j - qr
                    if ((unsigned)lc < 64u)
                        sQE[(16 * w + 4 * g + i) * 70 + lc] = f2bf(aq[i]);
                }
            }
            {   // KE: E rows 16(3-w+cc)+r
                int er = 16 * (3 - w + cc) + r;
                bf16x8 e0 = *reinterpret_cast<const bf16x8*>(&sE[o64(er, g * 8)]);
                bf16x8 e1 = *reinterpret_cast<const bf16x8*>(&sE[o64(er, 32 + g * 8)]);
                f32x4 ak = (f32x4){0.f, 0.f, 0.f, 0.f};
                ak = __builtin_amdgcn_mfma_f32_16x16x32_bf16(kaf0, e0, ak, 0, 0, 0);
                ak = __builtin_amdgcn_mfma_f32_16x16x32_bf16(kaf1, e1, ak, 0, 0, 0);
#pragma unroll
                for (int i = 0; i < 4; ++i) {
                    int lc = 16 * cc + r + 4 * g + i - 15;     // = qr = j + kc - 63
                    if ((unsigned)lc < 64u)
                        sKE[(16 * w + 4 * g + i) * 70 + lc] = f2bf(ak[i]);
                }
            }
        }
        __builtin_amdgcn_s_setprio(0);
        __syncthreads();                       // B -> C (E consumed, tables ready)

        // ---- phase C: gather + online softmax; write P over E rows 0..63
        float p[4][4];
#pragma unroll
        for (int cf = 0; cf < 4; ++cf) {
#pragma unroll
            for (int i = 0; i < 4; ++i) {
                int qr = 16 * w + 4 * g + i;
                int kc = 16 * cf + r;
                p[cf][i] = (S[cf][i] + bf2f(sQE[qr * 70 + 63 - kc])
                                     + bf2f(sKE[kc * 70 + qr])) * 0.125f;
            }
        }
#pragma unroll
        for (int i = 0; i < 4; ++i) {
            float m0 = fmaxf(fmaxf(p[0][i], p[1][i]), fmaxf(p[2][i], p[3][i]));
#pragma unroll
            for (int off = 1; off < 16; off <<= 1) m0 = fmaxf(m0, __shfl_xor(m0, off));
            float mn = fmaxf(mrun[i], m0);
            float sc = __expf(mrun[i] - mn);
            mrun[i] = mn;
            float rsum = 0.f;
#pragma unroll
            for (int cf = 0; cf < 4; ++cf) {
                float e = __expf(p[cf][i] - mn);
                p[cf][i] = e;
                rsum += e;
            }
#pragma unroll
            for (int off = 1; off < 16; off <<= 1) rsum += __shfl_xor(rsum, off);
            lrun[i] = lrun[i] * sc + rsum;
#pragma unroll
            for (int cf = 0; cf < 4; ++cf) cacc[cf][i] *= sc;
        }
#pragma unroll
        for (int cf = 0; cf < 4; ++cf)
#pragma unroll
            for (int i = 0; i < 4; ++i)
                sE[o64(16 * w + 4 * g + i, 16 * cf + r)] = f2bf(p[cf][i]);
        __syncthreads();                       // C -> D

        // ---- phase D: PV
        __builtin_amdgcn_s_setprio(1);
        bf16x8 pf0 = *reinterpret_cast<const bf16x8*>(&sE[o64(16 * w + r, g * 8)]);
        bf16x8 pf1 = *reinterpret_cast<const bf16x8*>(&sE[o64(16 * w + r, 32 + g * 8)]);
#pragma unroll
        for (int cf = 0; cf < 4; ++cf) {
            bf16x8 vf0 = *reinterpret_cast<const bf16x8*>(&sVt[o64(16 * cf + r, g * 8)]);
            bf16x8 vf1 = *reinterpret_cast<const bf16x8*>(&sVt[o64(16 * cf + r, 32 + g * 8)]);
            cacc[cf] = __builtin_amdgcn_mfma_f32_16x16x32_bf16(pf0, vf0, cacc[cf], 0, 0, 0);
            cacc[cf] = __builtin_amdgcn_mfma_f32_16x16x32_bf16(pf1, vf1, cacc[cf], 0, 0, 0);
        }
        __builtin_amdgcn_s_setprio(0);
    }

    // ---- epilogue: write ctx as swizzled hi/lo A-tiles for the output GEMM
    float rinv[4];
#pragma unroll
    for (int i = 0; i < 4; ++i) rinv[i] = 1.0f / lrun[i];
#pragma unroll
    for (int cf = 0; cf < 4; ++cf) {
#pragma unroll
        for (int i = 0; i < 4; ++i) {
            int qr = 16 * w + 4 * g + i;
            float val = cacc[cf][i] * rinv[i];
            ushort hi = f2bf(val);
            ushort lo = f2bf(val - bf2f(hi));
            int m = b * Lc + l0 + qr;
            int c = h * HDc + 16 * cf + r;
            int off = ((m >> 7) * NKT + (c >> 5)) * 4096 + sw_us(m & 127, c & 31);
            ctxh[off] = hi;
            ctxl[off] = lo;
        }
    }
}

extern "C" void kernel_launch(void* const* d_in, const int* in_sizes, int n_in,
                              void* d_out, int out_size, void* d_ws, size_t ws_size,
                              hipStream_t stream) {
    const float* hs = (const float*)d_in[0];
    const float* Wq = (const float*)d_in[1];
    const float* bq = (const float*)d_in[2];
    const float* Wk = (const float*)d_in[3];
    const float* bk = (const float*)d_in[4];
    const float* Wv = (const float*)d_in[5];
    const float* bv = (const float*)d_in[6];
    const float* Wd = (const float*)d_in[7];
    const float* bd = (const float*)d_in[8];
    const float* Eg = (const float*)d_in[9];

    const size_t N = (size_t)Bc * Lc * Dc;               // 3,145,728
    ushort* p = (ushort*)d_ws;
    ushort* qbf   = p;               p += N;
    ushort* kbf   = p;               p += N;
    ushort* vbf   = p;               p += N;             // V^T [b,h,d,l]
    ushort* hsh   = p;               p += N;             // aliased: ctx_hi after QKV
    ushort* hsl   = p;               p += N;             // ctx_lo (attn-written)
    ushort* wqkvh = p;               p += (size_t)2304 * 768;
    ushort* Ebf   = p;               p += (size_t)2048 * HDc;   // padded to 2048 rows
    ushort* wdh   = p;               p += (size_t)768 * 768;
    ushort* wdl   = p;               p += (size_t)768 * 768;

    const int NE = (2 * 1024 - 1) * HDc;                 // 131,008
    const int NEP = 2048 * HDc;                          // 131,072 (padded)

    cvt_bf16_k<<<dim3(512), dim3(256), 0, stream>>>(Eg, Ebf, NE, NEP);
    prep_hs<<<dim3(1536), dim3(256), 0, stream>>>(hs, hsh);
    prep_w<<<dim3(1152), dim3(256), 0, stream>>>(Wq, Wk, Wv, Wd, wqkvh, wdh, wdl);

    gemm_qkv<<<dim3(18, 32), dim3(256), 0, stream>>>(
        hsh, wqkvh, bq, bk, bv, qbf, kbf, vbf);

    attn_mfma<<<dim3(16, Hc, Bc), dim3(256), 0, stream>>>(
        qbf, kbf, vbf, Ebf, hsh, hsl);                   // ctx overwrites hs tiles

    gemm_split<<<dim3(6, 32), dim3(256), 0, stream>>>(
        hsh, hsl, wdh, wdl, bd, (float*)d_out);
}

// Round 9
// 245.282 us; speedup vs baseline: 1.8217x; 1.0244x over previous
//
#include <hip/hip_runtime.h>
#include <hip/hip_bf16.h>
#include <math.h>

typedef __bf16 bf16x8 __attribute__((ext_vector_type(8)));
typedef float f32x4 __attribute__((ext_vector_type(4)));

#define AS1 __attribute__((address_space(1)))
#define AS3 __attribute__((address_space(3)))
typedef AS1 const void gvoid;
typedef AS3 void svoid;

namespace {
constexpr int Bc = 4, Lc = 1024, Dc = 768, Hc = 12, HDc = 64;
constexpr int NKT = 24;          // K tiles: 768 / 32
}

static __device__ __forceinline__ ushort f2bf(float f) {
    __hip_bfloat16 h = __float2bfloat16(f);
    return *reinterpret_cast<ushort*>(&h);
}
static __device__ __forceinline__ float bf2f(ushort u) {
    __hip_bfloat16 h;
    *reinterpret_cast<ushort*>(&h) = u;
    return __bfloat162float(h);
}

// offset (ushort units) within an 8 KB [128 rows][32 cols] bf16 tile,
// paired-row XOR swizzle (GEMM staging layout).
static __device__ __forceinline__ int sw_us(int row, int col) {
    int line = row >> 1;
    int slot = (((row & 1) << 2) + (col >> 3)) ^ (line & 7);
    return line * 64 + slot * 8 + (col & 7);
}

// offset (ushort units) in a [rows][64] bf16 tile, slot-XOR swizzled.
static __device__ __forceinline__ int o64(int row, int col) {
    return (row << 6) + ((((col >> 3) ^ (row & 7))) << 3) + (col & 7);
}

// ------- fp32 -> bf16 convert (dist_emb), zero-pad to 2048 rows ------------
__global__ void cvt_bf16_k(const float* __restrict__ in, ushort* __restrict__ out,
                           int n, int ntot) {
    int i = blockIdx.x * 256 + threadIdx.x;
    if (i < ntot) out[i] = (i < n) ? f2bf(in[i]) : (ushort)0;
}

// ---------------- hs [4096,768] fp32 -> tiled swizzled hi (bf16) -----------
__global__ __launch_bounds__(256) void prep_hs(const float* __restrict__ hs,
                                               ushort* __restrict__ oh) {
    int i = blockIdx.x * 256 + threadIdx.x;      // 4096*96
    int m = i / 96, c8 = i % 96;
    const float* src = hs + (size_t)m * Dc + c8 * 8;
    float4 x0 = *(const float4*)src;
    float4 x1 = *(const float4*)(src + 4);
    float xs[8] = {x0.x, x0.y, x0.z, x0.w, x1.x, x1.y, x1.z, x1.w};
    ushort hi[8];
#pragma unroll
    for (int j = 0; j < 8; ++j) hi[j] = f2bf(xs[j]);
    int col = c8 * 8, kt = col >> 5, kc = col & 31;
    int mt = m >> 7, row = m & 127;
    int off = (mt * NKT + kt) * 4096 + sw_us(row, kc);
    *(uint4*)(oh + off) = *(uint4*)hi;
}

// ------- W^T tiles: Wq|Wk|Wv packed [2304 n] hi-only; Wd [768 n] hi+lo -----
__global__ __launch_bounds__(256) void prep_w(
    const float* __restrict__ Wq, const float* __restrict__ Wk,
    const float* __restrict__ Wv, const float* __restrict__ Wd,
    ushort* __restrict__ qkvh,
    ushort* __restrict__ wdh, ushort* __restrict__ wdl) {
    int i = blockIdx.x * 256 + threadIdx.x;      // 768*384
    int k = i / 384, n8 = i % 384;
    int which = n8 / 96, nl = (n8 % 96) * 8;
    const float* W = which == 0 ? Wq : which == 1 ? Wk : which == 2 ? Wv : Wd;
    const float* src = W + (size_t)k * Dc + nl;
    float4 x0 = *(const float4*)src;
    float4 x1 = *(const float4*)(src + 4);
    float xs[8] = {x0.x, x0.y, x0.z, x0.w, x1.x, x1.y, x1.z, x1.w};
    int kt = k >> 5, kc = k & 31;
    ushort* dh = (which < 3) ? qkvh : wdh;
    int ngbase = (which < 3) ? which * Dc + nl : nl;
#pragma unroll
    for (int j = 0; j < 8; ++j) {
        float x = xs[j];
        ushort hi = f2bf(x);
        int ng = ngbase + j;
        int nt = ng >> 7, row = ng & 127;
        int off = (nt * NKT + kt) * 4096 + sw_us(row, kc);
        dh[off] = hi;
        if (which == 3) wdl[off] = f2bf(x - bf2f(hi));
    }
}

// ---------------- pure-bf16 MFMA GEMM: QKV projection ----------------------
// out: q/k head-major [b,h,l,d] bf16, v TRANSPOSED [b,h,d,l] bf16.
__global__ __launch_bounds__(256) void gemm_qkv(
    const ushort* __restrict__ Ah, const ushort* __restrict__ Bh,
    const float* __restrict__ b0, const float* __restrict__ b1,
    const float* __restrict__ b2,
    ushort* __restrict__ o0, ushort* __restrict__ o1, ushort* __restrict__ o2) {
    __shared__ uint4 lds4[2][512];   // Ah | Bh, 8 KB each

    const int nt = blockIdx.x, mt = blockIdx.y;
    const int tid = threadIdx.x, w = tid >> 6, lane = tid & 63;
    const int wr = w >> 1, wc = w & 1, r = lane & 15, g = lane >> 4;

    const ushort* gsrc = ((w < 2) ? Ah + (size_t)mt * NKT * 4096
                                  : Bh + (size_t)nt * NKT * 4096) + (w & 1) * 2048;
    ushort* ldst = (ushort*)&lds4[w >> 1][0] + (w & 1) * 2048;

    f32x4 acc[4][4];
#pragma unroll
    for (int a = 0; a < 4; ++a)
#pragma unroll
        for (int b = 0; b < 4; ++b) acc[a][b] = (f32x4){0.f, 0.f, 0.f, 0.f};

    for (int kt = 0; kt < NKT; ++kt) {
        __syncthreads();
        const ushort* s = gsrc + kt * 4096 + lane * 8;
#pragma unroll
        for (int c = 0; c < 4; ++c)
            __builtin_amdgcn_global_load_lds((gvoid*)(s + c * 512),
                                             (svoid*)(ldst + c * 512), 16, 0, 0);
        __syncthreads();

        bf16x8 af[4];
#pragma unroll
        for (int mf = 0; mf < 4; ++mf)
            af[mf] = *(const bf16x8*)((const ushort*)&lds4[0][0] +
                                      sw_us(wr * 64 + mf * 16 + r, g * 8));
#pragma unroll
        for (int nf = 0; nf < 4; ++nf) {
            bf16x8 bf = *(const bf16x8*)((const ushort*)&lds4[1][0] +
                                         sw_us(wc * 64 + nf * 16 + r, g * 8));
#pragma unroll
            for (int mf = 0; mf < 4; ++mf)
                acc[mf][nf] = __builtin_amdgcn_mfma_f32_16x16x32_bf16(af[mf], bf, acc[mf][nf], 0, 0, 0);
        }
    }

    const int which = nt / 6;
    const float* bias = which == 0 ? b0 : which == 1 ? b1 : b2;
    ushort* outp = which == 0 ? o0 : which == 1 ? o1 : o2;
    const int nbase = nt * 128 - which * Dc + wc * 64;
    if (which < 2) {
#pragma unroll
        for (int nf = 0; nf < 4; ++nf) {
            int nl = nbase + nf * 16 + r;
            float bb = bias[nl];
            int h = nl >> 6, d = nl & 63;
#pragma unroll
            for (int mf = 0; mf < 4; ++mf) {
                int mbase = mt * 128 + wr * 64 + mf * 16 + g * 4;
#pragma unroll
                for (int i = 0; i < 4; ++i) {
                    int m = mbase + i, bI = m >> 10, l = m & 1023;
                    outp[(((size_t)bI * Hc + h) * Lc + l) * HDc + d] =
                        f2bf(acc[mf][nf][i] + bb);
                }
            }
        }
    } else {   // V: transposed [b, h, d, l], vectorized along l
#pragma unroll
        for (int nf = 0; nf < 4; ++nf) {
            int nl = nbase + nf * 16 + r;
            float bb = bias[nl];
            int h = nl >> 6, d = nl & 63;
#pragma unroll
            for (int mf = 0; mf < 4; ++mf) {
                int mbase = mt * 128 + wr * 64 + mf * 16 + g * 4;
                int bI = mbase >> 10, l = mbase & 1023;
                ushort4 c;
                c.x = f2bf(acc[mf][nf][0] + bb);
                c.y = f2bf(acc[mf][nf][1] + bb);
                c.z = f2bf(acc[mf][nf][2] + bb);
                c.w = f2bf(acc[mf][nf][3] + bb);
                *(ushort4*)&outp[((size_t)(bI * Hc + h) * HDc + d) * Lc + l] = c;
            }
        }
    }
}

// ------- split-bf16 MFMA GEMM: out-proj, 128M x 64N tiles (384 blocks) -----
__global__ __launch_bounds__(256) void gemm_split(
    const ushort* __restrict__ Ah, const ushort* __restrict__ Al,
    const ushort* __restrict__ Bh, const ushort* __restrict__ Bl,
    const float* __restrict__ b0,
    float* __restrict__ of) {
    __shared__ ushort sA[2][4096];   // Ah | Al, 8 KB each
    __shared__ ushort sB[2][2048];   // Bh | Bl half-tiles, 4 KB each

    const int nt = blockIdx.x;       // 0..11, 64-wide N tiles
    const int mt = blockIdx.y;       // 0..31
    const int tid = threadIdx.x, w = tid >> 6, lane = tid & 63;
    const int wr = w >> 1, wc = w & 1, r = lane & 15, g = lane >> 4;
    const int nt2 = nt >> 1, nhalf = nt & 1;

    // 24 x 1KB chunks per K-step; wave w stages chunks [6w, 6w+6)
    const ushort* srcs[6];
    ushort* dsts[6];
#pragma unroll
    for (int j = 0; j < 6; ++j) {
        int c = 6 * w + j;
        if (c < 8)       { srcs[j] = Ah + (size_t)mt * NKT * 4096 + c * 512;
                           dsts[j] = &sA[0][0] + c * 512; }
        else if (c < 16) { srcs[j] = Al + (size_t)mt * NKT * 4096 + (c - 8) * 512;
                           dsts[j] = &sA[1][0] + (c - 8) * 512; }
        else if (c < 20) { srcs[j] = Bh + (size_t)nt2 * NKT * 4096 + nhalf * 2048 + (c - 16) * 512;
                           dsts[j] = &sB[0][0] + (c - 16) * 512; }
        else             { srcs[j] = Bl + (size_t)nt2 * NKT * 4096 + nhalf * 2048 + (c - 20) * 512;
                           dsts[j] = &sB[1][0] + (c - 20) * 512; }
    }

    f32x4 acc[4][2];
#pragma unroll
    for (int a = 0; a < 4; ++a)
#pragma unroll
        for (int b = 0; b < 2; ++b) acc[a][b] = (f32x4){0.f, 0.f, 0.f, 0.f};

    for (int kt = 0; kt < NKT; ++kt) {
        __syncthreads();
#pragma unroll
        for (int j = 0; j < 6; ++j)
            __builtin_amdgcn_global_load_lds((gvoid*)(srcs[j] + (size_t)kt * 4096 + lane * 8),
                                             (svoid*)(dsts[j]), 16, 0, 0);
        __syncthreads();

        bf16x8 af[4][2];
#pragma unroll
        for (int mf = 0; mf < 4; ++mf) {
            int off = sw_us(wr * 64 + mf * 16 + r, g * 8);
            af[mf][0] = *(const bf16x8*)(&sA[0][0] + off);
            af[mf][1] = *(const bf16x8*)(&sA[1][0] + off);
        }
#pragma unroll
        for (int nf = 0; nf < 2; ++nf) {
            int off = sw_us(nhalf * 64 + wc * 32 + nf * 16 + r, g * 8) - nhalf * 2048;
            bf16x8 bh = *(const bf16x8*)(&sB[0][0] + off);
            bf16x8 bl = *(const bf16x8*)(&sB[1][0] + off);
#pragma unroll
            for (int mf = 0; mf < 4; ++mf) {
                acc[mf][nf] = __builtin_amdgcn_mfma_f32_16x16x32_bf16(af[mf][0], bh, acc[mf][nf], 0, 0, 0);
                acc[mf][nf] = __builtin_amdgcn_mfma_f32_16x16x32_bf16(af[mf][0], bl, acc[mf][nf], 0, 0, 0);
                acc[mf][nf] = __builtin_amdgcn_mfma_f32_16x16x32_bf16(af[mf][1], bh, acc[mf][nf], 0, 0, 0);
            }
        }
    }

#pragma unroll
    for (int nf = 0; nf < 2; ++nf) {
        int n = nt * 64 + wc * 32 + nf * 16 + r;
        float bb = b0[n];
#pragma unroll
        for (int mf = 0; mf < 4; ++mf) {
            int mbase = mt * 128 + wr * 64 + mf * 16 + g * 4;
#pragma unroll
            for (int i = 0; i < 4; ++i) {
                int m = mbase + i;
                of[(size_t)m * Dc + n] = acc[mf][nf][i] + bb;
            }
        }
    }
}

// ---------------- Fused relative-position attention (MFMA) -----------------
// R7 structure + T14 register prefetch (stage t+1 loads overlap phases B-D)
// + C->D barrier removed (P rows are wave-local). 3 barriers/iter.
__global__ __launch_bounds__(256, 3) void attn_mfma(
    const ushort* __restrict__ qg, const ushort* __restrict__ kg,
    const ushort* __restrict__ vtg, const ushort* __restrict__ Eb,
    ushort* __restrict__ ctxh, ushort* __restrict__ ctxl)
{
    const int b = blockIdx.z, h = blockIdx.y;
    const int l0 = blockIdx.x * 64;
    const size_t bh = (size_t)(b * Hc + h) * Lc * HDc;
    const ushort* qh = qg + bh;
    const ushort* kh = kg + bh;
    const ushort* vth = vtg + bh;     // [d][l], row stride Lc

    __shared__ ushort sK[64 * 64];    //  8192 B, swizzled
    __shared__ ushort sVt[64 * 64];   //  8192 B, swizzled [dim][key]
    __shared__ ushort sE[128 * 64];   // 16384 B, swizzled; rows 0..63 reused as P
    __shared__ ushort sQE[64 * 70];   //  8960 B  compact QE table
    __shared__ ushort sKE[64 * 70];   //  8960 B  compact KE table

    const int tid = threadIdx.x;
    const int lane = tid & 63;
    const int w = tid >> 6;           // wave, strip rows 16w..16w+15
    const int g = lane >> 4;
    const int r = lane & 15;

    const int rowA = tid >> 3;        // 0..31
    const int segA = tid & 7;

    bf16x8 qf0, qf1;
    {
        const ushort* qrow = qh + (size_t)(l0 + 16 * w + r) * 64;
        qf0 = *reinterpret_cast<const bf16x8*>(qrow + g * 8);
        qf1 = *reinterpret_cast<const bf16x8*>(qrow + 32 + g * 8);
    }

    // T14 prefetch registers (tile t+1): K rows rowA, rowA+32; Vt same; E rows rowA+32k
    uint4 rK0, rK1, rV0, rV1, rE0, rE1, rE2, rE3;
    auto ISSUE = [&](int r0) {
        rK0 = *(const uint4*)(kh + (size_t)(r0 + rowA) * 64 + segA * 8);
        rK1 = *(const uint4*)(kh + (size_t)(r0 + rowA + 32) * 64 + segA * 8);
        rV0 = *(const uint4*)(vth + (size_t)rowA * Lc + r0 + segA * 8);
        rV1 = *(const uint4*)(vth + (size_t)(rowA + 32) * Lc + r0 + segA * 8);
        int jb = l0 - r0 + 960;       // jb+127 <= 2047: padded E row is zeros,
                                      // and row-127 outputs are guarded (lc>=64)
        rE0 = *(const uint4*)(Eb + (size_t)(jb + rowA) * 64 + segA * 8);
        rE1 = *(const uint4*)(Eb + (size_t)(jb + rowA + 32) * 64 + segA * 8);
        rE2 = *(const uint4*)(Eb + (size_t)(jb + rowA + 64) * 64 + segA * 8);
        rE3 = *(const uint4*)(Eb + (size_t)(jb + rowA + 96) * 64 + segA * 8);
    };
    ISSUE(0);

    f32x4 cacc[4];
#pragma unroll
    for (int cf = 0; cf < 4; ++cf) cacc[cf] = (f32x4){0.f, 0.f, 0.f, 0.f};
    float mrun[4], lrun[4];
#pragma unroll
    for (int i = 0; i < 4; ++i) { mrun[i] = -1e30f; lrun[i] = 0.f; }

    for (int r0 = 0; r0 < Lc; r0 += 64) {
        __syncthreads();                       // all waves done with prev tiles
        // ---- stage from prefetch regs (swizzled)
        {
            int d0 = (rowA << 6) + ((segA ^ (rowA & 7)) << 3);
            int d1 = d0 + 32 * 64;             // (rowA+32)&7 == rowA&7
            *(uint4*)&sK[d0] = rK0;  *(uint4*)&sK[d1] = rK1;
            *(uint4*)&sVt[d0] = rV0; *(uint4*)&sVt[d1] = rV1;
            *(uint4*)&sE[d0] = rE0;
            *(uint4*)&sE[d0 + 32 * 64] = rE1;
            *(uint4*)&sE[d0 + 64 * 64] = rE2;
            *(uint4*)&sE[d0 + 96 * 64] = rE3;
        }
        if (r0 + 64 < Lc) ISSUE(r0 + 64);      // overlap with phases B-D
        __syncthreads();                       // tiles ready

        // ---- phase B: QK^T + compact QE/KE tables (5 fragments each)
        __builtin_amdgcn_s_setprio(1);
        f32x4 S[4];
#pragma unroll
        for (int cf = 0; cf < 4; ++cf) {
            f32x4 acc = (f32x4){0.f, 0.f, 0.f, 0.f};
            bf16x8 kf0 = *reinterpret_cast<const bf16x8*>(&sK[o64(16 * cf + r, g * 8)]);
            bf16x8 kf1 = *reinterpret_cast<const bf16x8*>(&sK[o64(16 * cf + r, 32 + g * 8)]);
            acc = __builtin_amdgcn_mfma_f32_16x16x32_bf16(qf0, kf0, acc, 0, 0, 0);
            acc = __builtin_amdgcn_mfma_f32_16x16x32_bf16(qf1, kf1, acc, 0, 0, 0);
            S[cf] = acc;
        }
        bf16x8 kaf0 = *reinterpret_cast<const bf16x8*>(&sK[o64(16 * w + r, g * 8)]);
        bf16x8 kaf1 = *reinterpret_cast<const bf16x8*>(&sK[o64(16 * w + r, 32 + g * 8)]);
#pragma unroll
        for (int cc = 0; cc < 5; ++cc) {
            {   // QE: E rows 16(w+cc)+r
                int er = 16 * (w + cc) + r;
                bf16x8 e0 = *reinterpret_cast<const bf16x8*>(&sE[o64(er, g * 8)]);
                bf16x8 e1 = *reinterpret_cast<const bf16x8*>(&sE[o64(er, 32 + g * 8)]);
                f32x4 aq = (f32x4){0.f, 0.f, 0.f, 0.f};
                aq = __builtin_amdgcn_mfma_f32_16x16x32_bf16(qf0, e0, aq, 0, 0, 0);
                aq = __builtin_amdgcn_mfma_f32_16x16x32_bf16(qf1, e1, aq, 0, 0, 0);
#pragma unroll
                for (int i = 0; i < 4; ++i) {
                    int lc = 16 * cc + r - 4 * g - i;          // = j - qr
                    if ((unsigned)lc < 64u)
                        sQE[(16 * w + 4 * g + i) * 70 + lc] = f2bf(aq[i]);
                }
            }
            {   // KE: E rows 16(3-w+cc)+r
                int er = 16 * (3 - w + cc) + r;
                bf16x8 e0 = *reinterpret_cast<const bf16x8*>(&sE[o64(er, g * 8)]);
                bf16x8 e1 = *reinterpret_cast<const bf16x8*>(&sE[o64(er, 32 + g * 8)]);
                f32x4 ak = (f32x4){0.f, 0.f, 0.f, 0.f};
                ak = __builtin_amdgcn_mfma_f32_16x16x32_bf16(kaf0, e0, ak, 0, 0, 0);
                ak = __builtin_amdgcn_mfma_f32_16x16x32_bf16(kaf1, e1, ak, 0, 0, 0);
#pragma unroll
                for (int i = 0; i < 4; ++i) {
                    int lc = 16 * cc + r + 4 * g + i - 15;     // = qr = j + kc - 63
                    if ((unsigned)lc < 64u)
                        sKE[(16 * w + 4 * g + i) * 70 + lc] = f2bf(ak[i]);
                }
            }
        }
        __builtin_amdgcn_s_setprio(0);
        __syncthreads();                       // B -> C (E consumed, tables ready)

        // ---- phase C: gather + online softmax; write P over E rows 0..63
        float p[4][4];
#pragma unroll
        for (int cf = 0; cf < 4; ++cf) {
#pragma unroll
            for (int i = 0; i < 4; ++i) {
                int qr = 16 * w + 4 * g + i;
                int kc = 16 * cf + r;
                p[cf][i] = (S[cf][i] + bf2f(sQE[qr * 70 + 63 - kc])
                                     + bf2f(sKE[kc * 70 + qr])) * 0.125f;
            }
        }
#pragma unroll
        for (int i = 0; i < 4; ++i) {
            float m0 = fmaxf(fmaxf(p[0][i], p[1][i]), fmaxf(p[2][i], p[3][i]));
#pragma unroll
            for (int off = 1; off < 16; off <<= 1) m0 = fmaxf(m0, __shfl_xor(m0, off));
            float mn = fmaxf(mrun[i], m0);
            float sc = __expf(mrun[i] - mn);
            mrun[i] = mn;
            float rsum = 0.f;
#pragma unroll
            for (int cf = 0; cf < 4; ++cf) {
                float e = __expf(p[cf][i] - mn);
                p[cf][i] = e;
                rsum += e;
            }
#pragma unroll
            for (int off = 1; off < 16; off <<= 1) rsum += __shfl_xor(rsum, off);
            lrun[i] = lrun[i] * sc + rsum;
#pragma unroll
            for (int cf = 0; cf < 4; ++cf) cacc[cf][i] *= sc;
        }
#pragma unroll
        for (int cf = 0; cf < 4; ++cf)
#pragma unroll
            for (int i = 0; i < 4; ++i)
                sE[o64(16 * w + 4 * g + i, 16 * cf + r)] = f2bf(p[cf][i]);
        // NO barrier: P rows [16w,16w+16) are written and read by the same wave

        // ---- phase D: PV
        __builtin_amdgcn_s_setprio(1);
        bf16x8 pf0 = *reinterpret_cast<const bf16x8*>(&sE[o64(16 * w + r, g * 8)]);
        bf16x8 pf1 = *reinterpret_cast<const bf16x8*>(&sE[o64(16 * w + r, 32 + g * 8)]);
#pragma unroll
        for (int cf = 0; cf < 4; ++cf) {
            bf16x8 vf0 = *reinterpret_cast<const bf16x8*>(&sVt[o64(16 * cf + r, g * 8)]);
            bf16x8 vf1 = *reinterpret_cast<const bf16x8*>(&sVt[o64(16 * cf + r, 32 + g * 8)]);
            cacc[cf] = __builtin_amdgcn_mfma_f32_16x16x32_bf16(pf0, vf0, cacc[cf], 0, 0, 0);
            cacc[cf] = __builtin_amdgcn_mfma_f32_16x16x32_bf16(pf1, vf1, cacc[cf], 0, 0, 0);
        }
        __builtin_amdgcn_s_setprio(0);
    }

    // ---- epilogue: write ctx as swizzled hi/lo A-tiles for the output GEMM
    float rinv[4];
#pragma unroll
    for (int i = 0; i < 4; ++i) rinv[i] = 1.0f / lrun[i];
#pragma unroll
    for (int cf = 0; cf < 4; ++cf) {
#pragma unroll
        for (int i = 0; i < 4; ++i) {
            int qr = 16 * w + 4 * g + i;
            float val = cacc[cf][i] * rinv[i];
            ushort hi = f2bf(val);
            ushort lo = f2bf(val - bf2f(hi));
            int m = b * Lc + l0 + qr;
            int c = h * HDc + 16 * cf + r;
            int off = ((m >> 7) * NKT + (c >> 5)) * 4096 + sw_us(m & 127, c & 31);
            ctxh[off] = hi;
            ctxl[off] = lo;
        }
    }
}

extern "C" void kernel_launch(void* const* d_in, const int* in_sizes, int n_in,
                              void* d_out, int out_size, void* d_ws, size_t ws_size,
                              hipStream_t stream) {
    const float* hs = (const float*)d_in[0];
    const float* Wq = (const float*)d_in[1];
    const float* bq = (const float*)d_in[2];
    const float* Wk = (const float*)d_in[3];
    const float* bk = (const float*)d_in[4];
    const float* Wv = (const float*)d_in[5];
    const float* bv = (const float*)d_in[6];
    const float* Wd = (const float*)d_in[7];
    const float* bd = (const float*)d_in[8];
    const float* Eg = (const float*)d_in[9];

    const size_t N = (size_t)Bc * Lc * Dc;               // 3,145,728
    ushort* p = (ushort*)d_ws;
    ushort* qbf   = p;               p += N;
    ushort* kbf   = p;               p += N;
    ushort* vbf   = p;               p += N;             // V^T [b,h,d,l]
    ushort* hsh   = p;               p += N;             // aliased: ctx_hi after QKV
    ushort* hsl   = p;               p += N;             // ctx_lo (attn-written)
    ushort* wqkvh = p;               p += (size_t)2304 * 768;
    ushort* Ebf   = p;               p += (size_t)2048 * HDc;   // padded to 2048 rows
    ushort* wdh   = p;               p += (size_t)768 * 768;
    ushort* wdl   = p;               p += (size_t)768 * 768;

    const int NE = (2 * 1024 - 1) * HDc;                 // 131,008
    const int NEP = 2048 * HDc;                          // 131,072 (padded)

    cvt_bf16_k<<<dim3(512), dim3(256), 0, stream>>>(Eg, Ebf, NE, NEP);
    prep_hs<<<dim3(1536), dim3(256), 0, stream>>>(hs, hsh);
    prep_w<<<dim3(1152), dim3(256), 0, stream>>>(Wq, Wk, Wv, Wd, wqkvh, wdh, wdl);

    gemm_qkv<<<dim3(18, 32), dim3(256), 0, stream>>>(
        hsh, wqkvh, bq, bk, bv, qbf, kbf, vbf);

    attn_mfma<<<dim3(16, Hc, Bc), dim3(256), 0, stream>>>(
        qbf, kbf, vbf, Ebf, hsh, hsl);                   // ctx overwrites hs tiles

    gemm_split<<<dim3(12, 32), dim3(256), 0, stream>>>(
        hsh, hsl, wdh, wdl, bd, (float*)d_out);
}